// Round 12
// baseline (189.271 us; speedup 1.0000x reference)
//
#include <hip/hip_runtime.h>

constexpr int Bn  = 4;
constexpr int Sn  = 1024;
constexpr int Dn  = 1024;
constexpr int Hn  = 16;
constexpr int HDn = 64;

using short8   = __attribute__((ext_vector_type(8))) short;
using float4v  = __attribute__((ext_vector_type(4))) float;
using float16v = __attribute__((ext_vector_type(16))) float;

__device__ __forceinline__ ushort f2bf(float f) {
    union { float f; unsigned u; } v; v.f = f;
    unsigned r = v.u + 0x7fff + ((v.u >> 16) & 1);   // RNE
    return (ushort)(r >> 16);
}

__device__ __forceinline__ void gload16(const void* g, void* l) {
    __builtin_amdgcn_global_load_lds(
        (const __attribute__((address_space(1))) void*)g,
        (__attribute__((address_space(3))) void*)l, 16, 0, 0);
}

// ---------------------------------------------------------------------------
// prep — ONE dispatch, 3328 blocks (R11-proven):
//   [0,2048)    convert_x | [2048,2816) transpose_w | [2816,3328) mask+copy
// ---------------------------------------------------------------------------
__global__ __launch_bounds__(256) void prep(
    const float* __restrict__ x,
    const float* __restrict__ Wq, const float* __restrict__ Wk,
    const float* __restrict__ Wv, const float* __restrict__ adj,
    ushort* __restrict__ xb, ushort* __restrict__ Wt, uint* __restrict__ Mb,
    float* __restrict__ out)
{
    const int bx  = blockIdx.x;
    const int tid = threadIdx.x;
    __shared__ __align__(16) ushort pool[64 * 72];   // 9216 B, aliased by msk

    if (bx < 2048) {
        const size_t i = ((size_t)bx * 256 + tid) * 8;
        float4 a = *(const float4*)&x[i];
        float4 b = *(const float4*)&x[i + 4];
        ushort o[8] = {f2bf(a.x), f2bf(a.y), f2bf(a.z), f2bf(a.w),
                       f2bf(b.x), f2bf(b.y), f2bf(b.z), f2bf(b.w)};
        *(uint4*)&xb[i] = *(const uint4*)o;
    } else if (bx < 2816) {
        const int idx = bx - 2048;
        const int which = idx >> 8, rem = idx & 255;
        const float* __restrict__ W = (which == 0) ? Wq : (which == 1) ? Wk : Wv;
        ushort* __restrict__ O = Wt + (size_t)which * Dn * Dn;
        const int k0 = (rem & 15) * 64, n0 = (rem >> 4) * 64;
        ushort* T = pool;

        const int kl = tid >> 4, nl = (tid & 15) * 4;
#pragma unroll
        for (int p = 0; p < 4; ++p) {
            float4 w4 = *(const float4*)&W[(size_t)(k0 + p * 16 + kl) * Dn + n0 + nl];
            T[(nl + 0) * 72 + p * 16 + kl] = f2bf(w4.x);
            T[(nl + 1) * 72 + p * 16 + kl] = f2bf(w4.y);
            T[(nl + 2) * 72 + p * 16 + kl] = f2bf(w4.z);
            T[(nl + 3) * 72 + p * 16 + kl] = f2bf(w4.w);
        }
        __syncthreads();
        const int nr = tid >> 2, kc = (tid & 3) * 16;
        uint4 u0 = *(const uint4*)&T[nr * 72 + kc];
        uint4 u1 = *(const uint4*)&T[nr * 72 + kc + 8];
        *(uint4*)&O[(size_t)(n0 + nr) * Dn + k0 + kc]     = u0;
        *(uint4*)&O[(size_t)(n0 + nr) * Dn + k0 + kc + 8] = u1;
    } else {
        const int idx = bx - 2816;                 // 0..511
        const int kt = idx & 15, qt = (idx >> 4) & 7, b = idx >> 7;
        char* msk = (char*)pool;                   // [128][68], 8704 B <= 9216

        float* ocopy = out + (size_t)Bn * Sn * Dn;
        const int r16 = tid >> 4, c4 = (tid & 15) * 4;
#pragma unroll
        for (int p = 0; p < 8; ++p) {
            const int row = p * 16 + r16;
            const size_t gi = ((size_t)b * Sn + qt * 128 + row) * Sn + kt * 64 + c4;
            float4 a = *(const float4*)&adj[gi];
            *(float4*)&ocopy[gi] = a;
            char* mr = &msk[row * 68 + c4];
            mr[0] = a.x >= 0.5f; mr[1] = a.y >= 0.5f;
            mr[2] = a.z >= 0.5f; mr[3] = a.w >= 0.5f;
        }
        __syncthreads();

        const int lane = tid & 63, w = tid >> 6;
        const int col = lane & 31, hi = lane >> 5;
        uint words[16];
#pragma unroll
        for (int mt = 0; mt < 2; ++mt)
#pragma unroll
            for (int pr = 0; pr < 8; ++pr) {
                const int r0 = 2 * pr;
                const int kl = mt * 32 + (r0 & 3) + 8 * (r0 >> 2) + 4 * hi;
                const char* mr = &msk[(w * 32 + col) * 68];
                words[mt * 8 + pr] = (mr[kl]     ? 0x0000FFFFu : 0u) |
                                     (mr[kl + 1] ? 0xFFFF0000u : 0u);
            }
        uint* dst = Mb + ((((size_t)(b * 8 + qt) * 16 + kt) * 4 + w) * 64 + lane) * 16;
#pragma unroll
        for (int c = 0; c < 4; ++c)
            *(uint4*)&dst[c * 4] =
                make_uint4(words[c*4], words[c*4+1], words[c*4+2], words[c*4+3]);
    }
}

// ---------------------------------------------------------------------------
// bf16 MFMA GEMM (R7/R11-proven): Q pre-scaled by 0.125*log2(e);
// Q/K -> [B,H,S,HD], V -> [B,H,HD,S]. Scatter epilogue (16-lane 32 B runs).
// ---------------------------------------------------------------------------
__global__ __launch_bounds__(256) void qkv_gemm(
    const ushort* __restrict__ xb, const ushort* __restrict__ Wt,
    const float* __restrict__ bq, const float* __restrict__ bk,
    const float* __restrict__ bv,
    ushort* __restrict__ Qb, ushort* __restrict__ Kb, ushort* __restrict__ Vb)
{
    const int which = blockIdx.z;
    const ushort* __restrict__ Bw   = Wt + (size_t)which * Dn * Dn;
    const float* __restrict__  bias = (which == 0) ? bq : (which == 1) ? bk : bv;
    ushort* __restrict__       Out  = (which == 0) ? Qb : (which == 1) ? Kb : Vb;
    const float scale = (which == 0) ? 0.18033688011112042f : 1.0f;  // 0.125*log2(e)

    const int n0   = blockIdx.x * 128;
    const int m0   = blockIdx.y * 128;
    const int tid  = threadIdx.x;
    const int wave = tid >> 6;
    const int lane = tid & 63;
    const int wm   = wave >> 1;
    const int wn   = wave & 1;

    __shared__ __align__(16) ushort As[128 * 32];
    __shared__ __align__(16) ushort Bs[128 * 32];

    const int L0 = wave * 64 + lane;
    const int r0s = L0 >> 2, c0s = (L0 & 3) * 8;
    const int L1 = L0 + 256;
    const int r1s = L1 >> 2, c1s = (L1 & 3) * 8;

    const ushort* pA0 = &xb[(size_t)(m0 + r0s) * Dn + c0s];
    const ushort* pA1 = &xb[(size_t)(m0 + r1s) * Dn + c1s];
    const ushort* pB0 = &Bw[(size_t)(n0 + r0s) * Dn + c0s];
    const ushort* pB1 = &Bw[(size_t)(n0 + r1s) * Dn + c1s];

    char* ldsA0 = (char*)As + wave * 1024;
    char* ldsA1 = (char*)As + wave * 1024 + 4096;
    char* ldsB0 = (char*)Bs + wave * 1024;
    char* ldsB1 = (char*)Bs + wave * 1024 + 4096;

    const int mlane = lane & 15;
    const int kg    = (lane >> 4) * 8;

    float4v acc[4][4];
    const float4v z4 = {0.f, 0.f, 0.f, 0.f};
#pragma unroll
    for (int i = 0; i < 4; ++i)
#pragma unroll
        for (int j = 0; j < 4; ++j) acc[i][j] = z4;

    for (int k0 = 0; k0 < Dn; k0 += 32) {
        __syncthreads();
        gload16(pA0, ldsA0);
        gload16(pA1, ldsA1);
        gload16(pB0, ldsB0);
        gload16(pB1, ldsB1);
        pA0 += 32; pA1 += 32; pB0 += 32; pB1 += 32;
        __syncthreads();

        short8 af[4], bf[4];
#pragma unroll
        for (int i = 0; i < 4; ++i)
            af[i] = *(const short8*)&As[(wm * 64 + i * 16 + mlane) * 32 + kg];
#pragma unroll
        for (int j = 0; j < 4; ++j)
            bf[j] = *(const short8*)&Bs[(wn * 64 + j * 16 + mlane) * 32 + kg];
#pragma unroll
        for (int i = 0; i < 4; ++i)
#pragma unroll
            for (int j = 0; j < 4; ++j)
                acc[i][j] = __builtin_amdgcn_mfma_f32_16x16x32_bf16(af[i], bf[j], acc[i][j], 0, 0, 0);
    }

    const int rb  = (lane >> 4) * 4;
    const int col = lane & 15;
#pragma unroll
    for (int j = 0; j < 4; ++j) {
        const int n  = n0 + wn * 64 + j * 16 + col;
        const float bias_n = bias[n];
        const int h  = n >> 6;
        const int hd = n & 63;
#pragma unroll
        for (int i = 0; i < 4; ++i) {
#pragma unroll
            for (int r = 0; r < 4; ++r) {
                const int m = m0 + wm * 64 + i * 16 + rb + r;
                const int b = m >> 10;
                const int s = m & 1023;
                size_t addr;
                if (which == 2)
                    addr = (((size_t)(b * Hn + h)) * HDn + hd) * Sn + s;   // V transposed
                else
                    addr = (((size_t)(b * Hn + h)) * Sn + s) * HDn + hd;
                Out[addr] = f2bf((acc[i][j][r] + bias_n) * scale);
            }
        }
    }
}

// ---------------------------------------------------------------------------
// MFMA flash attention, 512-thread blocks = two independent kt-streams.
// Waves 0-3 (kh=0): q-subtiles jt=0..3, kt 0..7, own LDS stream 0.
// Waves 4-7 (kh=1): same q-subtiles,    kt 8..15, own LDS stream 1.
// Each stream double-buffered (R7 staging pattern). All waves productive
// every iteration; no-max softmax => partials exactly additive; one LDS
// combine at the end. grid (8,16,4) = 512 blocks = 2/CU = 16 waves/CU.
// LDS 72 KB (4 x 9216 B K + 4 x 9216 B V), stride 72, conflicts ~0.
// ---------------------------------------------------------------------------
__global__ __launch_bounds__(512, 4) void attn_mfma(
    const ushort* __restrict__ Q, const ushort* __restrict__ K,
    const ushort* __restrict__ Vt, const uint* __restrict__ Mw,
    float* __restrict__ out)
{
    const int qt = blockIdx.x, h = blockIdx.y, b = blockIdx.z;
    const int tid  = threadIdx.x;
    const int w    = tid >> 6, lane = tid & 63;
    const int col  = lane & 31, hi = lane >> 5;
    const int jt   = w & 3, kh = w >> 2;
    const int st   = tid >> 8;          // staging stream (== kh for this thread's wave)
    const int t2   = tid & 255;

    const size_t hb = ((size_t)(b * Hn + h)) * Sn * HDn;
    const ushort* Kg = K + hb;          // [key][dim]
    const ushort* Vg = Vt + hb;         // [dim][key]

    __shared__ __align__(16) ushort Ks[4][64 * 72];   // [stream*2 + buf]
    __shared__ __align__(16) ushort Vs[4][64 * 72];

    // Q B-frags (registers): n = q-col, k = kp*16 + hi*8 + i
    short8 qf[4];
#pragma unroll
    for (int kp = 0; kp < 4; ++kp)
        qf[kp] = *(const short8*)&Q[hb +
            (size_t)(qt * 128 + jt * 32 + col) * HDn + kp * 16 + hi * 8];

    float16v o_[2];
#pragma unroll
    for (int dt = 0; dt < 2; ++dt)
#pragma unroll
        for (int r = 0; r < 16; ++r) o_[dt][r] = 0.f;
    float ls = 0.f;

    // staging (within stream st): chunk c -> row c>>3, 8-elem chunk (c&7)
    const int c0 = t2, c1 = t2 + 256;
    const int la0 = (c0 >> 3) * 72 + (c0 & 7) * 8;
    const int la1 = (c1 >> 3) * 72 + (c1 & 7) * 8;
    const int kt0 = st * 8;             // stream's first kt

    uint4 k0 = *(const uint4*)&Kg[(size_t)(kt0 * 64 + (c0 >> 3)) * HDn + (c0 & 7) * 8];
    uint4 k1 = *(const uint4*)&Kg[(size_t)(kt0 * 64 + (c1 >> 3)) * HDn + (c1 & 7) * 8];
    uint4 v0 = *(const uint4*)&Vg[(size_t)(c0 >> 3) * Sn + kt0 * 64 + (c0 & 7) * 8];
    uint4 v1 = *(const uint4*)&Vg[(size_t)(c1 >> 3) * Sn + kt0 * 64 + (c1 & 7) * 8];
    *(uint4*)&Ks[st * 2][la0] = k0;  *(uint4*)&Ks[st * 2][la1] = k1;
    *(uint4*)&Vs[st * 2][la0] = v0;  *(uint4*)&Vs[st * 2][la1] = v1;
    __syncthreads();

    // mask: q-subtile dim is jt here
    const uint* mbase = Mw + ((size_t)((b * 8 + qt) * 16) * 4 + jt) * 1024 + lane * 16;

    for (int i = 0; i < 8; ++i) {
        const int cur = i & 1;
        if (i < 7) {   // prefetch stream's next kt tile (global -> regs)
            const int nk = kt0 + i + 1;
            k0 = *(const uint4*)&Kg[(size_t)(nk * 64 + (c0 >> 3)) * HDn + (c0 & 7) * 8];
            k1 = *(const uint4*)&Kg[(size_t)(nk * 64 + (c1 >> 3)) * HDn + (c1 & 7) * 8];
            v0 = *(const uint4*)&Vg[(size_t)(c0 >> 3) * Sn + nk * 64 + (c0 & 7) * 8];
            v1 = *(const uint4*)&Vg[(size_t)(c1 >> 3) * Sn + nk * 64 + (c1 & 7) * 8];
        }
        const uint* mp = mbase + (size_t)(kh * 8 + i) * 4096;
        uint4 mk4[4];
        mk4[0] = *(const uint4*)(mp);
        mk4[1] = *(const uint4*)(mp + 4);
        mk4[2] = *(const uint4*)(mp + 8);
        mk4[3] = *(const uint4*)(mp + 12);
        const uint* mka = (const uint*)mk4;   // [mt*8 + pr]

        const ushort* KsC = Ks[kh * 2 + cur];
        const ushort* VsC = Vs[kh * 2 + cur];

#pragma unroll
        for (int mt = 0; mt < 2; ++mt) {
            float16v s_;
#pragma unroll
            for (int r = 0; r < 16; ++r) s_[r] = 0.f;
#pragma unroll
            for (int kp = 0; kp < 4; ++kp) {
                short8 ak = *(const short8*)&KsC[(mt * 32 + col) * 72 + kp * 16 + hi * 8];
                s_ = __builtin_amdgcn_mfma_f32_32x32x16_bf16(ak, qf[kp], s_, 0, 0, 0);
            }

            unsigned up[8];
#pragma unroll
            for (int pr = 0; pr < 8; ++pr) {
                const unsigned e0 = __float_as_uint(exp2f(s_[2 * pr]))     + 0x8000u;
                const unsigned e1 = __float_as_uint(exp2f(s_[2 * pr + 1])) + 0x8000u;
                const unsigned u  = __builtin_amdgcn_perm(e1, e0, 0x07060302u) & mka[mt * 8 + pr];
                up[pr] = u;
                ls += __uint_as_float(u << 16) + __uint_as_float(u & 0xffff0000u);
            }

#pragma unroll
            for (int kkh = 0; kkh < 2; ++kkh) {
                const unsigned a0 = up[kkh * 4 + 0], a1 = up[kkh * 4 + 1];
                const unsigned a2 = up[kkh * 4 + 2], a3 = up[kkh * 4 + 3];
                const unsigned t0 = (unsigned)__shfl_xor((int)(hi ? a0 : a2), 32, 64);
                const unsigned t1 = (unsigned)__shfl_xor((int)(hi ? a1 : a3), 32, 64);
                union { short8 s; unsigned u[4]; } f;
                f.u[0] = hi ? t0 : a0;
                f.u[1] = hi ? t1 : a1;
                f.u[2] = hi ? a2 : t0;
                f.u[3] = hi ? a3 : t1;
                const int kp = mt * 2 + kkh;
#pragma unroll
                for (int dt = 0; dt < 2; ++dt) {
                    short8 av = *(const short8*)&VsC[(dt * 32 + col) * 72 + kp * 16 + hi * 8];
                    o_[dt] = __builtin_amdgcn_mfma_f32_32x32x16_bf16(av, f.s, o_[dt], 0, 0, 0);
                }
            }
        }

        if (i < 7) {
            const int nxt = cur ^ 1;
            *(uint4*)&Ks[st * 2 + nxt][la0] = k0;  *(uint4*)&Ks[st * 2 + nxt][la1] = k1;
            *(uint4*)&Vs[st * 2 + nxt][la0] = v0;  *(uint4*)&Vs[st * 2 + nxt][la1] = v1;
        }
        __syncthreads();
    }

    // ---- combine kh partials (exactly additive) via Ks scratch ----
    float* red = (float*)Ks;    // 4 jt x 64 lanes x 34 floats = 34816 B <= 36864
    if (kh == 1) {
        float* p = red + (size_t)(jt * 64 + lane) * 34;
#pragma unroll
        for (int dt = 0; dt < 2; ++dt)
#pragma unroll
            for (int c = 0; c < 4; ++c)
                *(float4*)&p[dt * 16 + c * 4] = make_float4(
                    o_[dt][c * 4 + 0], o_[dt][c * 4 + 1],
                    o_[dt][c * 4 + 2], o_[dt][c * 4 + 3]);
        p[32] = ls;
    }
    __syncthreads();
    if (kh == 0) {
        const float* p = red + (size_t)(jt * 64 + lane) * 34;
#pragma unroll
        for (int dt = 0; dt < 2; ++dt)
#pragma unroll
            for (int r = 0; r < 16; ++r) o_[dt][r] += p[dt * 16 + r];
        ls += p[32];

        float l = ls + (float)__shfl_xor((float)ls, 32, 64);
        const float inv = 1.0f / l;
        const int q = qt * 128 + jt * 32 + col;
        float* op = &out[((size_t)b * Sn + q) * Dn + h * 64];
#pragma unroll
        for (int dt = 0; dt < 2; ++dt)
#pragma unroll
            for (int rg = 0; rg < 4; ++rg) {
                const int d = dt * 32 + rg * 8 + hi * 4;
                float4 o4;
                o4.x = fmaxf(o_[dt][rg * 4 + 0] * inv, 0.0f);
                o4.y = fmaxf(o_[dt][rg * 4 + 1] * inv, 0.0f);
                o4.z = fmaxf(o_[dt][rg * 4 + 2] * inv, 0.0f);
                o4.w = fmaxf(o_[dt][rg * 4 + 3] * inv, 0.0f);
                *(float4*)&op[d] = o4;
            }
    }
}

extern "C" void kernel_launch(void* const* d_in, const int* in_sizes, int n_in,
                              void* d_out, int out_size, void* d_ws, size_t ws_size,
                              hipStream_t stream)
{
    const float* x   = (const float*)d_in[0];
    const float* adj = (const float*)d_in[1];
    const float* Wq  = (const float*)d_in[2];
    const float* bq  = (const float*)d_in[3];
    const float* Wk  = (const float*)d_in[4];
    const float* bk  = (const float*)d_in[5];
    const float* Wv  = (const float*)d_in[6];
    const float* bv  = (const float*)d_in[7];
    float* out = (float*)d_out;

    // ws (ushort): xb[4.19M] | Wt[3.15M] | Qb | Kb | Vb [4.19M ea] then Mb (uint, 8.4 MB)
    ushort* xb = (ushort*)d_ws;
    ushort* Wt = xb + (size_t)Bn * Sn * Dn;
    ushort* Qb = Wt + (size_t)3 * Dn * Dn;
    ushort* Kb = Qb + (size_t)Bn * Hn * Sn * HDn;
    ushort* Vb = Kb + (size_t)Bn * Hn * Sn * HDn;
    uint*   Mb = (uint*)(Vb + (size_t)Bn * Hn * Sn * HDn);

    prep<<<dim3(3328), 256, 0, stream>>>(x, Wq, Wk, Wv, adj, xb, Wt, Mb, out);

    qkv_gemm<<<dim3(Dn / 128, (Bn * Sn) / 128, 3), 256, 0, stream>>>(
        xb, Wt, bq, bk, bv, Qb, Kb, Vb);

    attn_mfma<<<dim3(8, Hn, Bn), 512, 0, stream>>>(Qb, Kb, Vb, Mb, out);
}